// Round 7
// baseline (74.156 us; speedup 1.0000x reference)
//
#include <hip/hip_runtime.h>
#include <hip/hip_bf16.h>

// Resonance synth: out(b,e,n) = sum_f env_f(n) * sin(2*pi*freq_f*(n+1))
//   freq_f = (MIN + SCALE*f0_be)*(f+1), aliased (>=1.0) harmonics contribute 0
//   env_f(n) = linear frame->sample interp of res^(t+1), 256 samples/frame.
//
// Round 7: occupancy push. Chebyshev harmonic recurrence (1 sin + 1 cos per
// sample, s_{f+1}=2cos(theta)s_f - s_{f-1}) with state E[32]+temps ~50 VGPR
// -> fits the 64-VGPR cap of __launch_bounds__(256,8): 8 blocks/CU,
// 32 waves/CU = 8 waves/SIMD (2x round 6) to hide the serial-chain latency.
// Phase is a running u32 add (qn += Q1*256 mod 2^32) - no per-k mul_lo.

#define NSAMP 32768
#define NFRM  128
#define NF    32
#define NPAIR 64
#define CHUNKS 32
#define CHUNK (NSAMP / CHUNKS)   // 1024 samples per block
#define KIT   (CHUNK / 256)      // 4 samples per thread, 4 frames per block

__device__ __forceinline__ float ldin(const void* p, int i, bool isbf) {
    if (isbf) {
        unsigned int w = ((unsigned int)((const unsigned short*)p)[i]) << 16;
        float f; __builtin_memcpy(&f, &w, 4); return f;
    }
    return ((const float*)p)[i];
}

// force a block-uniform float into an SGPR
__device__ __forceinline__ float rfl(float x) {
    int i; __builtin_memcpy(&i, &x, 4);
    i = __builtin_amdgcn_readfirstlane(i);
    float f; __builtin_memcpy(&f, &i, 4); return f;
}

extern "C" __global__ __launch_bounds__(256, 8)
void reson_kernel(const void* __restrict__ f0p,
                  const void* __restrict__ resp,
                  const void* __restrict__ facp,
                  void* __restrict__ outp)
{
    // dtype sniff: factors[0]==1.0f -> f32 word 0x3F800000; bf16 packs 0x40003F80
    const bool isbf = (((const unsigned int*)facp)[0] != 0x3F800000u);

    const int pair = blockIdx.x;             // 0..63
    const int y    = blockIdx.y;             // 0..31
    const int tid  = threadIdx.x;            // 0..255
    const int n0   = y * CHUNK + tid;

    const float MINF = (float)(40.0 / 11025.0);
    const float FSC  = (float)(3960.0 / 11025.0);

    __shared__ float sR[NF];
    __shared__ float sP[NF];                 // r^(4y), alias-masked to 0

    const float f0v = rfl(ldin(f0p, pair, isbf));
    const float sf0 = MINF + FSC * f0v;      // < 0.37
    const unsigned int Q1 = (unsigned int)((double)sf0 * 4294967296.0 + 0.5);
    const unsigned int Qs = Q1 << 8;         // phase step per k (256 samples)

    if (tid < NF) {
        const float r   = ldin(resp, pair * NF + tid, isbf);
        const float fac = ldin(facp, tid, isbf);
        float P = exp2f(log2f(r) * (float)(4 * y));   // r^(4y); y==0 -> 1
        if (sf0 * fac >= 1.0f) P = 0.0f;              // aliased harmonic
        sR[tid] = r;
        sP[tid] = P;
    }
    __syncthreads();

    const float c0raw = (n0 + 0.5f) * (1.0f / 256.0f) - 0.5f;
    // frame-endpoint exponent i0c+1 is 4y (lo half, y>0) or 4y+1 (hi half / y==0)
    const bool useR1 = (tid >= 128) || (y == 0);

    float E[NF];     // per-thread env state
    float Rg[NF];    // block-uniform -> SGPRs
    #pragma unroll
    for (int f4 = 0; f4 < NF; f4 += 4) {
        const float4 p4 = *(const float4*)&sP[f4];   // ds_read_b128, broadcast
        const float4 r4 = *(const float4*)&sR[f4];
        Rg[f4+0] = rfl(r4.x); Rg[f4+1] = rfl(r4.y);
        Rg[f4+2] = rfl(r4.z); Rg[f4+3] = rfl(r4.w);
        E[f4+0] = useR1 ? p4.x * Rg[f4+0] : p4.x;
        E[f4+1] = useR1 ? p4.y * Rg[f4+1] : p4.y;
        E[f4+2] = useR1 ? p4.z * Rg[f4+2] : p4.z;
        E[f4+3] = useR1 ? p4.w * Rg[f4+3] : p4.w;
    }

    const int obase = pair * NSAMP + n0;
    unsigned int qn = Q1 * (unsigned int)(n0 + 1);   // phase of first sample

    if (y != 0 && y != CHUNKS - 1) {
        // ---- interior: fold w0 once, then env_k = env_0 * r^k ----
        const float w0 = c0raw - floorf(c0raw);      // no clamps possible
        #pragma unroll
        for (int f = 0; f < NF; ++f) {
            const float M = E[f];
            E[f] = fmaf(w0, fmaf(M, Rg[f], -M), M);  // M + w0*(M*r - M)
        }
        #pragma unroll 1
        for (int k = 0; k < KIT; ++k) {
            const float t  = (float)qn * 0x1p-32f;    // [0,1) revolutions
            const float s1 = __builtin_amdgcn_sinf(t);
            const float c1 = __builtin_amdgcn_cosf(t);
            const float k2 = c1 + c1;                 // 2*cos(theta)
            float sp = 0.0f, sc = s1;                 // sin(0), sin(theta)
            float a0 = 0.0f, a1 = 0.0f;
            #pragma unroll
            for (int f = 0; f < NF; ++f) {
                if (f & 1) a1 = fmaf(E[f], sc, a1);
                else       a0 = fmaf(E[f], sc, a0);
                E[f] *= Rg[f];
                const float sn = fmaf(k2, sc, -sp);   // sin((f+2)*theta)
                sp = sc; sc = sn;
            }
            const float acc = a0 + a1;
            const int o = obase + (k << 8);
            if (isbf) ((__hip_bfloat16*)outp)[o] = __float2bfloat16(acc);
            else      ((float*)outp)[o] = acc;
            qn += Qs;                                  // exact mod-2^32 advance
        }
    } else {
        // ---- edge blocks (y==0 clamp-low, y==31 clamp-high): general interp ----
        const float c0 = fminf(fmaxf(c0raw, 0.0f), 127.0f);
        const float w0 = c0 - floorf(c0);
        const float c1e = c0raw + 1.0f;
        const float w1 = c1e - floorf(c1e);
        const bool clampLow = (y == 0) && (c0raw < 0.0f);
        #pragma unroll 1
        for (int k = 0; k < KIT; ++k) {
            const float t  = (float)qn * 0x1p-32f;
            const float s1 = __builtin_amdgcn_sinf(t);
            const float cc = __builtin_amdgcn_cosf(t);
            const float k2 = cc + cc;
            float sp = 0.0f, sc = s1;
            const float wk = (k == 0)
                ? w0 : ((c0raw + (float)k > 127.0f) ? 0.0f : w1);
            const bool adv = !((k == 0) && clampLow); // clamped lanes hold frame 0
            float a0 = 0.0f, a1 = 0.0f;
            #pragma unroll
            for (int f = 0; f < NF; ++f) {
                const float M   = E[f];
                const float An  = M * Rg[f];
                const float env = fmaf(wk, An - M, M);
                if (f & 1) a1 = fmaf(env, sc, a1);
                else       a0 = fmaf(env, sc, a0);
                E[f] = adv ? An : M;
                const float sn = fmaf(k2, sc, -sp);
                sp = sc; sc = sn;
            }
            const float acc = a0 + a1;
            const int o = obase + (k << 8);
            if (isbf) ((__hip_bfloat16*)outp)[o] = __float2bfloat16(acc);
            else      ((float*)outp)[o] = acc;
            qn += Qs;
        }
    }
}

extern "C" void kernel_launch(void* const* d_in, const int* in_sizes, int n_in,
                              void* d_out, int out_size, void* d_ws, size_t ws_size,
                              hipStream_t stream) {
    (void)in_sizes; (void)n_in; (void)out_size; (void)d_ws; (void)ws_size;
    dim3 grid(NPAIR, CHUNKS);   // 64 x 32 = 2048 blocks = 8 blocks/CU
    dim3 block(256);
    reson_kernel<<<grid, block, 0, stream>>>(d_in[0], d_in[1], d_in[2], d_out);
}

// Round 8
// 67.285 us; speedup vs baseline: 1.1021x; 1.1021x over previous
//
#include <hip/hip_runtime.h>
#include <hip/hip_bf16.h>

// Resonance synth: out(b,e,n) = sum_f env_f(n) * sin(2*pi*freq_f*(n+1))
//   freq_f = (MIN + SCALE*f0_be)*(f+1), aliased (>=1.0) harmonics contribute 0
//   env_f(n) = linear frame->sample interp of res^(t+1), 256 samples/frame.
//
// Round 8: 4-way ILP. R6 config ((256,4), CHUNKS=16 -- measured best) but the
// interior processes 4 samples per pass with 4 INDEPENDENT Chebyshev chains
// (s_{f+1}=2cos(theta_j)s_f - s_{f-1}), sharing the envelope walk
// e1=e0*R, e2=e1*R, e3=e2*R, E=e3*R (1 mul/sample, bit-identical to R6).
// Dependent-fma distance goes 3 ops -> ~12 ops: no latency bubbles; 4 chains
// x 4 waves/SIMD = 16 independent streams. ~58 VGPR, zero spill risk at the
// 128-VGPR cap. R7's (256,8) regression showed the 64-cap spills -- avoided.

#define NSAMP 32768
#define NFRM  128
#define NF    32
#define NPAIR 64
#define CHUNKS 16
#define CHUNK (NSAMP / CHUNKS)   // 2048 samples per block
#define KIT   (CHUNK / 256)      // 8 samples per thread = 2 groups of 4

__device__ __forceinline__ float ldin(const void* p, int i, bool isbf) {
    if (isbf) {
        unsigned int w = ((unsigned int)((const unsigned short*)p)[i]) << 16;
        float f; __builtin_memcpy(&f, &w, 4); return f;
    }
    return ((const float*)p)[i];
}

// force a block-uniform float into an SGPR
__device__ __forceinline__ float rfl(float x) {
    int i; __builtin_memcpy(&i, &x, 4);
    i = __builtin_amdgcn_readfirstlane(i);
    float f; __builtin_memcpy(&f, &i, 4); return f;
}

extern "C" __global__ __launch_bounds__(256, 4)
void reson_kernel(const void* __restrict__ f0p,
                  const void* __restrict__ resp,
                  const void* __restrict__ facp,
                  void* __restrict__ outp)
{
    // dtype sniff: factors[0]==1.0f -> f32 word 0x3F800000; bf16 packs 0x40003F80
    const bool isbf = (((const unsigned int*)facp)[0] != 0x3F800000u);

    const int pair = blockIdx.x;             // 0..63
    const int y    = blockIdx.y;             // 0..15
    const int tid  = threadIdx.x;            // 0..255
    const int n0   = y * CHUNK + tid;

    const float MINF = (float)(40.0 / 11025.0);
    const float FSC  = (float)(3960.0 / 11025.0);

    __shared__ float sR[NF];
    __shared__ float sP[NF];                 // r^(8y), alias-masked to 0

    const float f0v = rfl(ldin(f0p, pair, isbf));
    const float sf0 = MINF + FSC * f0v;      // < 0.37
    const unsigned int Q1 = (unsigned int)((double)sf0 * 4294967296.0 + 0.5);
    const unsigned int Qs = Q1 << 8;         // phase step per k (256 samples)

    if (tid < NF) {
        const float r   = ldin(resp, pair * NF + tid, isbf);
        const float fac = ldin(facp, tid, isbf);
        float P = exp2f(log2f(r) * (float)(8 * y));   // r^(8y); y==0 -> 1
        if (sf0 * fac >= 1.0f) P = 0.0f;              // aliased harmonic
        sR[tid] = r;
        sP[tid] = P;
    }
    __syncthreads();

    const float c0raw = (n0 + 0.5f) * (1.0f / 256.0f) - 0.5f;
    // frame-endpoint exponent i0c+1 is 8y (lo half, y>0) or 8y+1 (hi half / y==0)
    const bool useR1 = (tid >= 128) || (y == 0);

    float E[NF];     // per-thread env state
    float Rg[NF];    // block-uniform -> SGPRs
    #pragma unroll
    for (int f4 = 0; f4 < NF; f4 += 4) {
        const float4 p4 = *(const float4*)&sP[f4];   // ds_read_b128, broadcast
        const float4 r4 = *(const float4*)&sR[f4];
        Rg[f4+0] = rfl(r4.x); Rg[f4+1] = rfl(r4.y);
        Rg[f4+2] = rfl(r4.z); Rg[f4+3] = rfl(r4.w);
        E[f4+0] = useR1 ? p4.x * Rg[f4+0] : p4.x;
        E[f4+1] = useR1 ? p4.y * Rg[f4+1] : p4.y;
        E[f4+2] = useR1 ? p4.z * Rg[f4+2] : p4.z;
        E[f4+3] = useR1 ? p4.w * Rg[f4+3] : p4.w;
    }

    const int obase = pair * NSAMP + n0;
    unsigned int qn = Q1 * (unsigned int)(n0 + 1);   // phase of first sample

    if (y != 0 && y != CHUNKS - 1) {
        // ---- interior: fold w0 once, then env advances by *R per sample ----
        const float w0 = c0raw - floorf(c0raw);      // no clamps possible
        #pragma unroll
        for (int f = 0; f < NF; ++f) {
            const float M = E[f];
            E[f] = fmaf(w0, fmaf(M, Rg[f], -M), M);  // M + w0*(M*r - M)
        }
        #pragma unroll 1
        for (int g = 0; g < KIT / 4; ++g) {
            // 4 base angles for samples g*4 .. g*4+3
            const unsigned int q0 = qn;
            const unsigned int q1 = qn + Qs;
            const unsigned int q2 = q1 + Qs;
            const unsigned int q3 = q2 + Qs;
            const float s0 = __builtin_amdgcn_sinf((float)q0 * 0x1p-32f);
            const float c0 = __builtin_amdgcn_cosf((float)q0 * 0x1p-32f);
            const float s1 = __builtin_amdgcn_sinf((float)q1 * 0x1p-32f);
            const float c1 = __builtin_amdgcn_cosf((float)q1 * 0x1p-32f);
            const float s2 = __builtin_amdgcn_sinf((float)q2 * 0x1p-32f);
            const float c2 = __builtin_amdgcn_cosf((float)q2 * 0x1p-32f);
            const float s3 = __builtin_amdgcn_sinf((float)q3 * 0x1p-32f);
            const float c3 = __builtin_amdgcn_cosf((float)q3 * 0x1p-32f);
            const float k20 = c0 + c0, k21 = c1 + c1;
            const float k22 = c2 + c2, k23 = c3 + c3;
            float sp0 = 0.f, sc0 = s0, sp1 = 0.f, sc1 = s1;
            float sp2 = 0.f, sc2 = s2, sp3 = 0.f, sc3 = s3;
            float a0 = 0.f, a1 = 0.f, a2 = 0.f, a3 = 0.f;
            #pragma unroll
            for (int f = 0; f < NF; ++f) {
                const float r  = Rg[f];
                const float e0 = E[f];
                const float e1 = e0 * r;
                const float e2 = e1 * r;
                const float e3 = e2 * r;
                a0 = fmaf(e0, sc0, a0);
                a1 = fmaf(e1, sc1, a1);
                a2 = fmaf(e2, sc2, a2);
                a3 = fmaf(e3, sc3, a3);
                E[f] = e3 * r;
                const float n0c = fmaf(k20, sc0, -sp0); sp0 = sc0; sc0 = n0c;
                const float n1c = fmaf(k21, sc1, -sp1); sp1 = sc1; sc1 = n1c;
                const float n2c = fmaf(k22, sc2, -sp2); sp2 = sc2; sc2 = n2c;
                const float n3c = fmaf(k23, sc3, -sp3); sp3 = sc3; sc3 = n3c;
            }
            const int o = obase + (g << 10);          // g*4 samples * 256
            if (isbf) {
                __hip_bfloat16* op = (__hip_bfloat16*)outp;
                op[o]       = __float2bfloat16(a0);
                op[o + 256] = __float2bfloat16(a1);
                op[o + 512] = __float2bfloat16(a2);
                op[o + 768] = __float2bfloat16(a3);
            } else {
                float* op = (float*)outp;
                op[o] = a0; op[o + 256] = a1; op[o + 512] = a2; op[o + 768] = a3;
            }
            qn = q3 + Qs;                             // exact mod-2^32 advance
        }
    } else {
        // ---- edge blocks (y==0 clamp-low, y==15 clamp-high): general interp ----
        const float c0 = fminf(fmaxf(c0raw, 0.0f), 127.0f);
        const float w0 = c0 - floorf(c0);
        const float c1e = c0raw + 1.0f;
        const float w1 = c1e - floorf(c1e);
        const bool clampLow = (y == 0) && (c0raw < 0.0f);
        #pragma unroll 1
        for (int k = 0; k < KIT; ++k) {
            const float t  = (float)qn * 0x1p-32f;
            const float s1 = __builtin_amdgcn_sinf(t);
            const float cc = __builtin_amdgcn_cosf(t);
            const float k2 = cc + cc;
            float sp = 0.0f, sc = s1;
            const float wk = (k == 0)
                ? w0 : ((c0raw + (float)k > 127.0f) ? 0.0f : w1);
            const bool adv = !((k == 0) && clampLow); // clamped lanes hold frame 0
            float a0 = 0.0f, a1 = 0.0f;
            #pragma unroll
            for (int f = 0; f < NF; ++f) {
                const float M   = E[f];
                const float An  = M * Rg[f];
                const float env = fmaf(wk, An - M, M);
                if (f & 1) a1 = fmaf(env, sc, a1);
                else       a0 = fmaf(env, sc, a0);
                E[f] = adv ? An : M;
                const float sn = fmaf(k2, sc, -sp);
                sp = sc; sc = sn;
            }
            const float acc = a0 + a1;
            const int o = obase + (k << 8);
            if (isbf) ((__hip_bfloat16*)outp)[o] = __float2bfloat16(acc);
            else      ((float*)outp)[o] = acc;
            qn += Qs;
        }
    }
}

extern "C" void kernel_launch(void* const* d_in, const int* in_sizes, int n_in,
                              void* d_out, int out_size, void* d_ws, size_t ws_size,
                              hipStream_t stream) {
    (void)in_sizes; (void)n_in; (void)out_size; (void)d_ws; (void)ws_size;
    dim3 grid(NPAIR, CHUNKS);   // 64 x 16 = 1024 blocks = 4 blocks/CU, tail-free
    dim3 block(256);
    reson_kernel<<<grid, block, 0, stream>>>(d_in[0], d_in[1], d_in[2], d_out);
}